// Round 1
// baseline (5344.260 us; speedup 1.0000x reference)
//
#include <hip/hip_runtime.h>
#include <math.h>

#define NN 50000
#define NE 800000

// ---------------- world-message kernel ----------------
// m_h_w[i] = relu([z_h[i], z_h[i,0:3]-pos] @ Ww1 + bw1) @ Ww2 + bw2
// m_agg_w  = sum_i m_h_w[i]   (64 floats, accumulated via block partials)
__global__ __launch_bounds__(256) void world_kernel(
    const float* __restrict__ z_h, const float* __restrict__ pos_world,
    const float* __restrict__ Ww1, const float* __restrict__ bw1,
    const float* __restrict__ Ww2, const float* __restrict__ bw2,
    float* __restrict__ m_agg_w)
{
    __shared__ float W1s[67 * 128];   // 34.3 KB
    __shared__ float b1s[128];
    __shared__ float red[64];
    int t = threadIdx.x;
    for (int i = t; i < 67 * 128; i += 256) W1s[i] = Ww1[i];
    if (t < 128) b1s[t] = bw1[t];
    if (t < 64) red[t] = 0.f;
    __syncthreads();

    int node = blockIdx.x * 256 + t;
    float out[64];
#pragma unroll
    for (int o = 0; o < 64; o++) out[o] = 0.f;

    if (node < NN) {
        float x[67];
        const float4* zr = (const float4*)(z_h + (long)node * 64);
#pragma unroll
        for (int k = 0; k < 16; k++) {
            float4 v = zr[k];
            x[4 * k + 0] = v.x; x[4 * k + 1] = v.y; x[4 * k + 2] = v.z; x[4 * k + 3] = v.w;
        }
        x[64] = x[0] - pos_world[0];
        x[65] = x[1] - pos_world[1];
        x[66] = x[2] - pos_world[2];
#pragma unroll
        for (int o = 0; o < 64; o++) out[o] = bw2[o];   // per-node bias

#pragma unroll 1
        for (int c = 0; c < 128; c += 4) {
            float h0 = b1s[c + 0], h1 = b1s[c + 1], h2 = b1s[c + 2], h3 = b1s[c + 3];
#pragma unroll
            for (int j = 0; j < 67; j++) {
                float xv = x[j];
                h0 += xv * W1s[j * 128 + c + 0];
                h1 += xv * W1s[j * 128 + c + 1];
                h2 += xv * W1s[j * 128 + c + 2];
                h3 += xv * W1s[j * 128 + c + 3];
            }
            h0 = fmaxf(h0, 0.f); h1 = fmaxf(h1, 0.f);
            h2 = fmaxf(h2, 0.f); h3 = fmaxf(h3, 0.f);
            const float* w2 = Ww2 + c * 64;
#pragma unroll
            for (int o = 0; o < 64; o++)
                out[o] += h0 * w2[o] + h1 * w2[64 + o] + h2 * w2[128 + o] + h3 * w2[192 + o];
        }
    }

    // wave butterfly reduce (64 lanes), then per-block LDS partial, then one
    // global atomic per channel per block
#pragma unroll
    for (int mask = 1; mask < 64; mask <<= 1) {
#pragma unroll
        for (int o = 0; o < 64; o++) out[o] += __shfl_xor(out[o], mask, 64);
    }
    if ((t & 63) == 0) {
#pragma unroll
        for (int o = 0; o < 64; o++) atomicAdd(&red[o], out[o]);
    }
    __syncthreads();
    if (t < 64) atomicAdd(&m_agg_w[t], red[t]);
}

// ---------------- edge kernel ----------------
// 64 edges per block, 256 threads. X tile [64][136] in LDS (stride 137),
// two half-hidden passes through Hs [64][64] (stride 65), message kept in
// registers (16 outputs per thread), gate computed without LDS hidden.
// Scatter: w * m atomicAdd'ed into m_agg_h (== d_out accumulator).
__global__ __launch_bounds__(256) void edge_kernel(
    const float* __restrict__ z_h, const int* __restrict__ ei,
    const float* __restrict__ We1, const float* __restrict__ be1,
    const float* __restrict__ We2, const float* __restrict__ be2,
    const float* __restrict__ Wg1, const float* __restrict__ bg1,
    const float* __restrict__ Wg2, const float* __restrict__ bg2,
    float* __restrict__ m_agg_h)
{
    __shared__ float X[64][137];    // 35.1 KB
    __shared__ float Hs[64][65];    // 16.6 KB
    __shared__ int   tgt_s[64];
    __shared__ float gred[4][64];
    __shared__ float wgt[64];

    int t = threadIdx.x;
    int e0 = blockIdx.x * 64;        // E = 800000 divisible by 64: no guards
    int e = t & 63, g = t >> 6;      // g in 0..3

    if (t < 64) tgt_s[t] = ei[NE + e0 + t];
    {
        int ee = t >> 2, q = t & 3;  // 4 threads per edge stage 16 floats each side
        int s = ei[e0 + ee];
        int d = ei[NE + e0 + ee];
        const float4* zs4 = (const float4*)(z_h + (long)s * 64);
        const float4* zt4 = (const float4*)(z_h + (long)d * 64);
#pragma unroll
        for (int k = 0; k < 4; k++) {
            float4 v = zs4[q * 4 + k];
            X[ee][q * 16 + k * 4 + 0] = v.x; X[ee][q * 16 + k * 4 + 1] = v.y;
            X[ee][q * 16 + k * 4 + 2] = v.z; X[ee][q * 16 + k * 4 + 3] = v.w;
            float4 u = zt4[q * 4 + k];
            X[ee][64 + q * 16 + k * 4 + 0] = u.x; X[ee][64 + q * 16 + k * 4 + 1] = u.y;
            X[ee][64 + q * 16 + k * 4 + 2] = u.z; X[ee][64 + q * 16 + k * 4 + 3] = u.w;
        }
    }
    __syncthreads();
    if (t < 64) {   // edge features -> X[t][128..135]
        float dx = X[t][0] - X[t][64], dy = X[t][1] - X[t][65], dz = X[t][2] - X[t][66];
        float ax = X[t][3], ay = X[t][4], az = X[t][5];
        float bx = X[t][67], by = X[t][68], bz = X[t][69];
        float cx = ay * bz - az * by;
        float cy = az * bx - ax * bz;
        float cz = ax * by - ay * bx;
        X[t][128] = dx; X[t][129] = dy; X[t][130] = dz;
        X[t][131] = dx * dx + dy * dy + dz * dz;
        X[t][132] = cx; X[t][133] = cy; X[t][134] = cz;
        X[t][135] = sqrtf(cx * cx + cy * cy + cz * cz);
    }
    __syncthreads();

    float m[16];
#pragma unroll
    for (int oo = 0; oo < 16; oo++) m[oo] = be2[g * 16 + oo];

    // ---- edge MLP: hidden in two halves of 64 channels ----
#pragma unroll 1
    for (int p = 0; p < 2; p++) {
#pragma unroll 1
        for (int cc = 0; cc < 2; cc++) {
            int cb = p * 64 + g * 16 + cc * 8;
            float h[8];
#pragma unroll
            for (int k = 0; k < 8; k++) h[k] = be1[cb + k];
            const float* w = We1 + cb;
#pragma unroll
            for (int j = 0; j < 136; j++) {
                float xv = X[e][j];
#pragma unroll
                for (int k = 0; k < 8; k++) h[k] += xv * w[j * 128 + k];
            }
#pragma unroll
            for (int k = 0; k < 8; k++) Hs[e][g * 16 + cc * 8 + k] = fmaxf(h[k], 0.f);
        }
        __syncthreads();
#pragma unroll 1
        for (int c2 = 0; c2 < 64; c2++) {
            float r = Hs[e][c2];
            const float* w2 = We2 + (p * 64 + c2) * 64 + g * 16;
#pragma unroll
            for (int oo = 0; oo < 16; oo++) m[oo] += r * w2[oo];
        }
        __syncthreads();   // Hs reused by next half / gate path done with X only
    }

    // ---- gate MLP: each thread owns 32 hidden channels, no LDS hidden ----
    float gp = 0.f;
#pragma unroll 1
    for (int cc = 0; cc < 4; cc++) {
        int cb = g * 32 + cc * 8;
        float h[8];
#pragma unroll
        for (int k = 0; k < 8; k++) h[k] = bg1[cb + k];
        const float* w = Wg1 + cb;
#pragma unroll
        for (int j = 0; j < 136; j++) {
            float xv = X[e][j];
#pragma unroll
            for (int k = 0; k < 8; k++) h[k] += xv * w[j * 128 + k];
        }
#pragma unroll
        for (int k = 0; k < 8; k++) gp += fmaxf(h[k], 0.f) * Wg2[cb + k];
    }
    gred[g][e] = gp;
    __syncthreads();
    if (t < 64) {
        float gg = bg2[0] + gred[0][t] + gred[1][t] + gred[2][t] + gred[3][t];
        wgt[t] = 1.f / (1.f + expf(-gg));
    }
    __syncthreads();

    {
        float wv = wgt[e];
        float* dst = m_agg_h + (long)tgt_s[e] * 64 + g * 16;
#pragma unroll
        for (int oo = 0; oo < 16; oo++) atomicAdd(dst + oo, wv * m[oo]);
    }
}

// ---------------- node kernel ----------------
// Reads m_agg rows from d_out (block-local rows only), overwrites with
// delta_z_h. 64 nodes per block.
__global__ __launch_bounds__(256) void node_kernel(
    const float* __restrict__ z_h,
    const float* __restrict__ m_agg_h, const float* __restrict__ m_agg_w,
    const float* __restrict__ Wn1, const float* __restrict__ bn1,
    const float* __restrict__ Wn2, const float* __restrict__ bn2,
    float* __restrict__ outp)
{
    __shared__ float X[64][129];    // 33.0 KB
    __shared__ float Hs[64][65];
    __shared__ float mw[64];
    int t = threadIdx.x;
    if (t < 64) mw[t] = m_agg_w[t];
    int n0 = blockIdx.x * 64;
    int e = t & 63, g = t >> 6;
    {
        int nn = t >> 2, q = t & 3;
        int node = n0 + nn;
        if (node >= NN) node = NN - 1;   // clamp stays inside this block's rows
        const float4* zr = (const float4*)(z_h + (long)node * 64);
        const float4* mr = (const float4*)(m_agg_h + (long)node * 64);
#pragma unroll
        for (int k = 0; k < 4; k++) {
            float4 v = zr[q * 4 + k];
            X[nn][q * 16 + k * 4 + 0] = v.x; X[nn][q * 16 + k * 4 + 1] = v.y;
            X[nn][q * 16 + k * 4 + 2] = v.z; X[nn][q * 16 + k * 4 + 3] = v.w;
            float4 u = mr[q * 4 + k];
            X[nn][64 + q * 16 + k * 4 + 0] = u.x; X[nn][64 + q * 16 + k * 4 + 1] = u.y;
            X[nn][64 + q * 16 + k * 4 + 2] = u.z; X[nn][64 + q * 16 + k * 4 + 3] = u.w;
        }
    }
    __syncthreads();
    for (int i = t; i < 64 * 64; i += 256) {        // add broadcast world message
        int r = i >> 6, c2 = i & 63;
        X[r][64 + c2] += mw[c2];
    }
    __syncthreads();

    float m[16];
#pragma unroll
    for (int oo = 0; oo < 16; oo++) m[oo] = bn2[g * 16 + oo];

#pragma unroll 1
    for (int p = 0; p < 2; p++) {
#pragma unroll 1
        for (int cc = 0; cc < 2; cc++) {
            int cb = p * 64 + g * 16 + cc * 8;
            float h[8];
#pragma unroll
            for (int k = 0; k < 8; k++) h[k] = bn1[cb + k];
            const float* w = Wn1 + cb;
#pragma unroll
            for (int j = 0; j < 128; j++) {
                float xv = X[e][j];
#pragma unroll
                for (int k = 0; k < 8; k++) h[k] += xv * w[j * 128 + k];
            }
#pragma unroll
            for (int k = 0; k < 8; k++) Hs[e][g * 16 + cc * 8 + k] = fmaxf(h[k], 0.f);
        }
        __syncthreads();
#pragma unroll 1
        for (int c2 = 0; c2 < 64; c2++) {
            float r = Hs[e][c2];
            const float* w2 = Wn2 + (p * 64 + c2) * 64 + g * 16;
#pragma unroll
            for (int oo = 0; oo < 16; oo++) m[oo] += r * w2[oo];
        }
        __syncthreads();
    }

    int node = n0 + e;
    if (node < NN) {
        float4* dst = (float4*)(outp + (long)node * 64 + g * 16);
        dst[0] = make_float4(m[0], m[1], m[2], m[3]);
        dst[1] = make_float4(m[4], m[5], m[6], m[7]);
        dst[2] = make_float4(m[8], m[9], m[10], m[11]);
        dst[3] = make_float4(m[12], m[13], m[14], m[15]);
    }
}

extern "C" void kernel_launch(void* const* d_in, const int* in_sizes, int n_in,
                              void* d_out, int out_size, void* d_ws, size_t ws_size,
                              hipStream_t stream)
{
    const float* z_h       = (const float*)d_in[0];
    const float* pos_world = (const float*)d_in[1];
    const int*   ei        = (const int*)d_in[2];
    const float* We1 = (const float*)d_in[3];  const float* be1 = (const float*)d_in[4];
    const float* We2 = (const float*)d_in[5];  const float* be2 = (const float*)d_in[6];
    const float* Wg1 = (const float*)d_in[7];  const float* bg1 = (const float*)d_in[8];
    const float* Wg2 = (const float*)d_in[9];  const float* bg2 = (const float*)d_in[10];
    const float* Wn1 = (const float*)d_in[11]; const float* bn1 = (const float*)d_in[12];
    const float* Wn2 = (const float*)d_in[13]; const float* bn2 = (const float*)d_in[14];
    const float* Ww1 = (const float*)d_in[15]; const float* bw1 = (const float*)d_in[16];
    const float* Ww2 = (const float*)d_in[17]; const float* bw2 = (const float*)d_in[18];

    float* outp    = (float*)d_out;
    float* m_agg_h = outp;             // d_out doubles as the scatter accumulator
    float* m_agg_w = (float*)d_ws;     // 64 floats of ws

    hipMemsetAsync(d_out, 0, (size_t)NN * 64 * sizeof(float), stream);
    hipMemsetAsync(d_ws, 0, 64 * sizeof(float), stream);

    world_kernel<<<(NN + 255) / 256, 256, 0, stream>>>(z_h, pos_world, Ww1, bw1, Ww2, bw2, m_agg_w);
    edge_kernel<<<NE / 64, 256, 0, stream>>>(z_h, ei, We1, be1, We2, be2,
                                             Wg1, bg1, Wg2, bg2, m_agg_h);
    node_kernel<<<(NN + 63) / 64, 256, 0, stream>>>(z_h, m_agg_h, m_agg_w,
                                                    Wn1, bn1, Wn2, bn2, outp);
}

// Round 2
// 915.557 us; speedup vs baseline: 5.8372x; 5.8372x over previous
//
#include <hip/hip_runtime.h>
#include <math.h>

#define NN 50000
#define NE 800000

typedef float  f32x4  __attribute__((ext_vector_type(4)));
typedef __bf16 bf16x8 __attribute__((ext_vector_type(8)));

__device__ inline bf16x8 pack8(float4 a, float4 b) {
    bf16x8 r;
    r[0] = (__bf16)a.x; r[1] = (__bf16)a.y; r[2] = (__bf16)a.z; r[3] = (__bf16)a.w;
    r[4] = (__bf16)b.x; r[5] = (__bf16)b.y; r[6] = (__bf16)b.z; r[7] = (__bf16)b.w;
    return r;
}

__device__ inline float4 addw(float4 v, const float* p) {
    v.x += p[0]; v.y += p[1]; v.z += p[2]; v.w += p[3]; return v;
}

// ---------------- world-message kernel (fp32 VALU, unchanged) ----------------
__global__ __launch_bounds__(256) void world_kernel(
    const float* __restrict__ z_h, const float* __restrict__ pos_world,
    const float* __restrict__ Ww1, const float* __restrict__ bw1,
    const float* __restrict__ Ww2, const float* __restrict__ bw2,
    float* __restrict__ m_agg_w)
{
    __shared__ float W1s[67 * 128];
    __shared__ float b1s[128];
    __shared__ float red[64];
    int t = threadIdx.x;
    for (int i = t; i < 67 * 128; i += 256) W1s[i] = Ww1[i];
    if (t < 128) b1s[t] = bw1[t];
    if (t < 64) red[t] = 0.f;
    __syncthreads();

    int node = blockIdx.x * 256 + t;
    float out[64];
#pragma unroll
    for (int o = 0; o < 64; o++) out[o] = 0.f;

    if (node < NN) {
        float x[67];
        const float4* zr = (const float4*)(z_h + (long)node * 64);
#pragma unroll
        for (int k = 0; k < 16; k++) {
            float4 v = zr[k];
            x[4 * k + 0] = v.x; x[4 * k + 1] = v.y; x[4 * k + 2] = v.z; x[4 * k + 3] = v.w;
        }
        x[64] = x[0] - pos_world[0];
        x[65] = x[1] - pos_world[1];
        x[66] = x[2] - pos_world[2];
#pragma unroll
        for (int o = 0; o < 64; o++) out[o] = bw2[o];

#pragma unroll 1
        for (int c = 0; c < 128; c += 4) {
            float h0 = b1s[c + 0], h1 = b1s[c + 1], h2 = b1s[c + 2], h3 = b1s[c + 3];
#pragma unroll
            for (int j = 0; j < 67; j++) {
                float xv = x[j];
                h0 += xv * W1s[j * 128 + c + 0];
                h1 += xv * W1s[j * 128 + c + 1];
                h2 += xv * W1s[j * 128 + c + 2];
                h3 += xv * W1s[j * 128 + c + 3];
            }
            h0 = fmaxf(h0, 0.f); h1 = fmaxf(h1, 0.f);
            h2 = fmaxf(h2, 0.f); h3 = fmaxf(h3, 0.f);
            const float* w2 = Ww2 + c * 64;
#pragma unroll
            for (int o = 0; o < 64; o++)
                out[o] += h0 * w2[o] + h1 * w2[64 + o] + h2 * w2[128 + o] + h3 * w2[192 + o];
        }
    }

#pragma unroll
    for (int mask = 1; mask < 64; mask <<= 1) {
#pragma unroll
        for (int o = 0; o < 64; o++) out[o] += __shfl_xor(out[o], mask, 64);
    }
    if ((t & 63) == 0) {
#pragma unroll
        for (int o = 0; o < 64; o++) atomicAdd(&red[o], out[o]);
    }
    __syncthreads();
    if (t < 64) atomicAdd(&m_agg_w[t], red[t]);
}

// ---------------- edge kernel: MFMA bf16 ----------------
// 64 edges/block, 256 threads = 4 waves.
// GEMM1: [64 x 160(pad)] @ [160 x 256]  (cols 0..127 = We1, 128..255 = Wg1)
// GEMM2: [64 x 128] @ [128 x 64]  (We2); gate = VALU dot over Hb cols 128..255
union EdgeLds {
    struct { __bf16 Xb[64][160]; __bf16 Wt[256][32]; } a;              // 36864 B
    struct { __bf16 Hb[64][264]; __bf16 W2t[64][136]; float gred[4][64]; } b; // 52224 B
};

__global__ __launch_bounds__(256) void edge_kernel(
    const float* __restrict__ z_h, const int* __restrict__ ei,
    const float* __restrict__ We1, const float* __restrict__ be1,
    const float* __restrict__ We2, const float* __restrict__ be2,
    const float* __restrict__ Wg1, const float* __restrict__ bg1,
    const float* __restrict__ Wg2, const float* __restrict__ bg2,
    float* __restrict__ m_agg_h)
{
    __shared__ EdgeLds L;
    __shared__ int   tgt_s[64];
    __shared__ float wgt[64];

    const int t = threadIdx.x;
    const int e0 = blockIdx.x * 64;          // NE % 64 == 0
    const int lane = t & 63, w = t >> 6;
    const int quad = lane >> 4, l16 = lane & 15;

    if (t < 64) tgt_s[t] = ei[NE + e0 + t];

    // ---- gather X tile (bf16), edge feats computed in fp32 from registers ----
    {
        const int ee = t >> 2, q = t & 3;
        const int s = ei[e0 + ee];
        const int d = ei[NE + e0 + ee];
        const float4* zs4 = (const float4*)(z_h + (long)s * 64) + q * 4;
        const float4* zt4 = (const float4*)(z_h + (long)d * 64) + q * 4;
        float4 s0 = zs4[0], s1 = zs4[1], s2 = zs4[2], s3 = zs4[3];
        float4 t0 = zt4[0], t1 = zt4[1], t2 = zt4[2], t3 = zt4[3];
        *(bf16x8*)&L.a.Xb[ee][q * 16]          = pack8(s0, s1);
        *(bf16x8*)&L.a.Xb[ee][q * 16 + 8]      = pack8(s2, s3);
        *(bf16x8*)&L.a.Xb[ee][64 + q * 16]     = pack8(t0, t1);
        *(bf16x8*)&L.a.Xb[ee][64 + q * 16 + 8] = pack8(t2, t3);
        if (q == 0) {
            float dx = s0.x - t0.x, dy = s0.y - t0.y, dz = s0.z - t0.z;
            float ax = s0.w, ay = s1.x, az = s1.y;
            float bx = t0.w, by = t1.x, bz = t1.y;
            float cx = ay * bz - az * by;
            float cy = az * bx - ax * bz;
            float cz = ax * by - ay * bx;
            bf16x8 f;
            f[0] = (__bf16)dx; f[1] = (__bf16)dy; f[2] = (__bf16)dz;
            f[3] = (__bf16)(dx * dx + dy * dy + dz * dz);
            f[4] = (__bf16)cx; f[5] = (__bf16)cy; f[6] = (__bf16)cz;
            f[7] = (__bf16)sqrtf(cx * cx + cy * cy + cz * cz);
            *(bf16x8*)&L.a.Xb[ee][128] = f;
            bf16x8 z;
#pragma unroll
            for (int i = 0; i < 8; i++) z[i] = (__bf16)0.f;
            *(bf16x8*)&L.a.Xb[ee][136] = z;
            *(bf16x8*)&L.a.Xb[ee][144] = z;
            *(bf16x8*)&L.a.Xb[ee][152] = z;
        }
    }

    // ---- GEMM1: acc1[mt][nt], wave handles 64 hidden cols ----
    const int colb = w * 64;
    f32x4 acc1[4][4];
#pragma unroll
    for (int nt = 0; nt < 4; nt++) {
        int col = colb + nt * 16 + l16;
        float b = (col < 128) ? be1[col] : bg1[col - 128];
#pragma unroll
        for (int mt = 0; mt < 4; mt++) { f32x4 v = {b, b, b, b}; acc1[mt][nt] = v; }
    }

#pragma unroll 1
    for (int kc = 0; kc < 5; kc++) {
        __syncthreads();
        {   // stage Wt[n=t][kk] = W1[kc*32+kk][t], zero past row 135
            const float* src = (t < 128) ? (We1 + t) : (Wg1 + (t - 128));
            const int r0 = kc * 32;
#pragma unroll
            for (int kk0 = 0; kk0 < 32; kk0 += 8) {
                bf16x8 p;
#pragma unroll
                for (int i = 0; i < 8; i++) {
                    int r = r0 + kk0 + i;
                    float v = (r < 136) ? src[(size_t)r * 128] : 0.f;
                    p[i] = (__bf16)v;
                }
                *(bf16x8*)&L.a.Wt[t][kk0] = p;
            }
        }
        __syncthreads();
        bf16x8 af[4], bfr[4];
#pragma unroll
        for (int mt = 0; mt < 4; mt++)
            af[mt] = *(const bf16x8*)&L.a.Xb[mt * 16 + l16][kc * 32 + quad * 8];
#pragma unroll
        for (int nt = 0; nt < 4; nt++)
            bfr[nt] = *(const bf16x8*)&L.a.Wt[colb + nt * 16 + l16][quad * 8];
#pragma unroll
        for (int mt = 0; mt < 4; mt++)
#pragma unroll
            for (int nt = 0; nt < 4; nt++)
                acc1[mt][nt] = __builtin_amdgcn_mfma_f32_16x16x32_bf16(
                    af[mt], bfr[nt], acc1[mt][nt], 0, 0, 0);
    }

    __syncthreads();   // all frag reads done; safe to overwrite union with phase B

    // ---- H (relu, bf16) -> Hb; stage We2^T ----
#pragma unroll
    for (int mt = 0; mt < 4; mt++)
#pragma unroll
        for (int nt = 0; nt < 4; nt++) {
            int col = colb + nt * 16 + l16;
#pragma unroll
            for (int r = 0; r < 4; r++)
                L.b.Hb[mt * 16 + quad * 4 + r][col] = (__bf16)fmaxf(acc1[mt][nt][r], 0.f);
        }
    {
        const int n = t & 63, half = t >> 6;
        const float* src = We2 + n;
#pragma unroll
        for (int kk0 = 0; kk0 < 32; kk0 += 8) {
            bf16x8 p;
#pragma unroll
            for (int i = 0; i < 8; i++)
                p[i] = (__bf16)src[(size_t)(half * 32 + kk0 + i) * 64];
            *(bf16x8*)&L.b.W2t[n][half * 32 + kk0] = p;
        }
    }
    __syncthreads();

    // ---- gate: per-thread partial over 32 gate-hidden channels ----
    {
        const int e = t & 63, p = t >> 6;
        float gp = 0.f;
#pragma unroll
        for (int j = 0; j < 32; j++)
            gp += (float)L.b.Hb[e][128 + p * 32 + j] * Wg2[p * 32 + j];
        L.b.gred[p][e] = gp;
    }
    __syncthreads();
    if (t < 64) {
        float g = bg2[0] + L.b.gred[0][t] + L.b.gred[1][t] + L.b.gred[2][t] + L.b.gred[3][t];
        wgt[t] = 1.f / (1.f + expf(-g));
    }
    __syncthreads();

    // ---- GEMM2: message = H[:,0:128] @ We2 + be2 ----
    f32x4 acc2[4];
    {
        float b2 = be2[w * 16 + l16];
#pragma unroll
        for (int mt = 0; mt < 4; mt++) { f32x4 v = {b2, b2, b2, b2}; acc2[mt] = v; }
    }
#pragma unroll
    for (int kc = 0; kc < 4; kc++) {
        bf16x8 bfr = *(const bf16x8*)&L.b.W2t[w * 16 + l16][kc * 32 + quad * 8];
#pragma unroll
        for (int mt = 0; mt < 4; mt++) {
            bf16x8 af = *(const bf16x8*)&L.b.Hb[mt * 16 + l16][kc * 32 + quad * 8];
            acc2[mt] = __builtin_amdgcn_mfma_f32_16x16x32_bf16(af, bfr, acc2[mt], 0, 0, 0);
        }
    }

    // ---- scatter: atomicAdd(w * m) into target rows ----
#pragma unroll
    for (int mt = 0; mt < 4; mt++)
#pragma unroll
        for (int r = 0; r < 4; r++) {
            int edge = mt * 16 + quad * 4 + r;
            float val = acc2[mt][r] * wgt[edge];
            atomicAdd(m_agg_h + (long)tgt_s[edge] * 64 + w * 16 + l16, val);
        }
}

// ---------------- node kernel: MFMA bf16 ----------------
// 64 nodes/block. GEMM1: [64 x 128] @ [128 x 128]; GEMM2: [64 x 128] @ [128 x 64]
union NodeLds {
    struct { __bf16 Xb[64][128]; __bf16 Wt[128][32]; } a;   // 24576 B
    struct { __bf16 Hb[64][136]; __bf16 W2t[64][136]; } b;  // 34816 B
};

__global__ __launch_bounds__(256) void node_kernel(
    const float* __restrict__ z_h,
    const float* __restrict__ m_agg_h, const float* __restrict__ m_agg_w,
    const float* __restrict__ Wn1, const float* __restrict__ bn1,
    const float* __restrict__ Wn2, const float* __restrict__ bn2,
    float* __restrict__ outp)
{
    __shared__ NodeLds L;
    __shared__ float mw[64];
    const int t = threadIdx.x;
    const int n0 = blockIdx.x * 64;
    const int lane = t & 63, w = t >> 6;
    const int quad = lane >> 4, l16 = lane & 15;

    if (t < 64) mw[t] = m_agg_w[t];
    __syncthreads();

    {   // gather [z | m_agg_h + mw] -> bf16
        const int nn = t >> 2, q = t & 3;
        int node = n0 + nn; if (node >= NN) node = NN - 1;   // clamp stays in-block
        const float4* zr = (const float4*)(z_h + (long)node * 64) + q * 4;
        const float4* mr = (const float4*)(m_agg_h + (long)node * 64) + q * 4;
        float4 z0 = zr[0], z1 = zr[1], z2 = zr[2], z3 = zr[3];
        *(bf16x8*)&L.a.Xb[nn][q * 16]     = pack8(z0, z1);
        *(bf16x8*)&L.a.Xb[nn][q * 16 + 8] = pack8(z2, z3);
        float4 m0 = mr[0], m1 = mr[1], m2 = mr[2], m3 = mr[3];
        const float* mwp = &mw[q * 16];
        m0 = addw(m0, mwp); m1 = addw(m1, mwp + 4);
        m2 = addw(m2, mwp + 8); m3 = addw(m3, mwp + 12);
        *(bf16x8*)&L.a.Xb[nn][64 + q * 16]     = pack8(m0, m1);
        *(bf16x8*)&L.a.Xb[nn][64 + q * 16 + 8] = pack8(m2, m3);
    }

    f32x4 acc1[4][2];
#pragma unroll
    for (int nt = 0; nt < 2; nt++) {
        float b = bn1[w * 32 + nt * 16 + l16];
#pragma unroll
        for (int mt = 0; mt < 4; mt++) { f32x4 v = {b, b, b, b}; acc1[mt][nt] = v; }
    }

#pragma unroll 1
    for (int kc = 0; kc < 4; kc++) {
        __syncthreads();
        {   // stage Wt[c][kk] = Wn1[kc*32+kk][c]
            const int c = t & 127, half = t >> 7;
            const float* src = Wn1 + c;
            const int r0 = kc * 32 + half * 16;
#pragma unroll
            for (int kk0 = 0; kk0 < 16; kk0 += 8) {
                bf16x8 p;
#pragma unroll
                for (int i = 0; i < 8; i++)
                    p[i] = (__bf16)src[(size_t)(r0 + kk0 + i) * 128];
                *(bf16x8*)&L.a.Wt[c][half * 16 + kk0] = p;
            }
        }
        __syncthreads();
        bf16x8 af[4], bfr[2];
#pragma unroll
        for (int mt = 0; mt < 4; mt++)
            af[mt] = *(const bf16x8*)&L.a.Xb[mt * 16 + l16][kc * 32 + quad * 8];
#pragma unroll
        for (int nt = 0; nt < 2; nt++)
            bfr[nt] = *(const bf16x8*)&L.a.Wt[w * 32 + nt * 16 + l16][quad * 8];
#pragma unroll
        for (int mt = 0; mt < 4; mt++)
#pragma unroll
            for (int nt = 0; nt < 2; nt++)
                acc1[mt][nt] = __builtin_amdgcn_mfma_f32_16x16x32_bf16(
                    af[mt], bfr[nt], acc1[mt][nt], 0, 0, 0);
    }

    __syncthreads();

#pragma unroll
    for (int mt = 0; mt < 4; mt++)
#pragma unroll
        for (int nt = 0; nt < 2; nt++) {
            int col = w * 32 + nt * 16 + l16;
#pragma unroll
            for (int r = 0; r < 4; r++)
                L.b.Hb[mt * 16 + quad * 4 + r][col] = (__bf16)fmaxf(acc1[mt][nt][r], 0.f);
        }
    {
        const int n = t & 63, half = t >> 6;
        const float* src = Wn2 + n;
#pragma unroll
        for (int kk0 = 0; kk0 < 32; kk0 += 8) {
            bf16x8 p;
#pragma unroll
            for (int i = 0; i < 8; i++)
                p[i] = (__bf16)src[(size_t)(half * 32 + kk0 + i) * 64];
            *(bf16x8*)&L.b.W2t[n][half * 32 + kk0] = p;
        }
    }
    __syncthreads();

    f32x4 acc2[4];
    {
        float b2 = bn2[w * 16 + l16];
#pragma unroll
        for (int mt = 0; mt < 4; mt++) { f32x4 v = {b2, b2, b2, b2}; acc2[mt] = v; }
    }
#pragma unroll
    for (int kc = 0; kc < 4; kc++) {
        bf16x8 bfr = *(const bf16x8*)&L.b.W2t[w * 16 + l16][kc * 32 + quad * 8];
#pragma unroll
        for (int mt = 0; mt < 4; mt++) {
            bf16x8 af = *(const bf16x8*)&L.b.Hb[mt * 16 + l16][kc * 32 + quad * 8];
            acc2[mt] = __builtin_amdgcn_mfma_f32_16x16x32_bf16(af, bfr, acc2[mt], 0, 0, 0);
        }
    }

#pragma unroll
    for (int mt = 0; mt < 4; mt++)
#pragma unroll
        for (int r = 0; r < 4; r++) {
            int node = n0 + mt * 16 + quad * 4 + r;
            if (node < NN)
                outp[(long)node * 64 + w * 16 + l16] = acc2[mt][r];
        }
}

extern "C" void kernel_launch(void* const* d_in, const int* in_sizes, int n_in,
                              void* d_out, int out_size, void* d_ws, size_t ws_size,
                              hipStream_t stream)
{
    const float* z_h       = (const float*)d_in[0];
    const float* pos_world = (const float*)d_in[1];
    const int*   ei        = (const int*)d_in[2];
    const float* We1 = (const float*)d_in[3];  const float* be1 = (const float*)d_in[4];
    const float* We2 = (const float*)d_in[5];  const float* be2 = (const float*)d_in[6];
    const float* Wg1 = (const float*)d_in[7];  const float* bg1 = (const float*)d_in[8];
    const float* Wg2 = (const float*)d_in[9];  const float* bg2 = (const float*)d_in[10];
    const float* Wn1 = (const float*)d_in[11]; const float* bn1 = (const float*)d_in[12];
    const float* Wn2 = (const float*)d_in[13]; const float* bn2 = (const float*)d_in[14];
    const float* Ww1 = (const float*)d_in[15]; const float* bw1 = (const float*)d_in[16];
    const float* Ww2 = (const float*)d_in[17]; const float* bw2 = (const float*)d_in[18];

    float* outp    = (float*)d_out;
    float* m_agg_h = outp;             // d_out doubles as the scatter accumulator
    float* m_agg_w = (float*)d_ws;     // 64 floats of ws

    hipMemsetAsync(d_out, 0, (size_t)NN * 64 * sizeof(float), stream);
    hipMemsetAsync(d_ws, 0, 64 * sizeof(float), stream);

    world_kernel<<<(NN + 255) / 256, 256, 0, stream>>>(z_h, pos_world, Ww1, bw1, Ww2, bw2, m_agg_w);
    edge_kernel<<<NE / 64, 256, 0, stream>>>(z_h, ei, We1, be1, We2, be2,
                                             Wg1, bg1, Wg2, bg2, m_agg_h);
    node_kernel<<<(NN + 63) / 64, 256, 0, stream>>>(z_h, m_agg_h, m_agg_w,
                                                    Wn1, bn1, Wn2, bn2, outp);
}

// Round 3
// 866.830 us; speedup vs baseline: 6.1653x; 1.0562x over previous
//
#include <hip/hip_runtime.h>
#include <math.h>

#define NN 50000
#define NE 800000

typedef float  f32x4  __attribute__((ext_vector_type(4)));
typedef __bf16 bf16x8 __attribute__((ext_vector_type(8)));

__device__ inline bf16x8 pack8(float4 a, float4 b) {
    bf16x8 r;
    r[0] = (__bf16)a.x; r[1] = (__bf16)a.y; r[2] = (__bf16)a.z; r[3] = (__bf16)a.w;
    r[4] = (__bf16)b.x; r[5] = (__bf16)b.y; r[6] = (__bf16)b.z; r[7] = (__bf16)b.w;
    return r;
}

__device__ inline float4 addw(float4 v, const float* p) {
    v.x += p[0]; v.y += p[1]; v.z += p[2]; v.w += p[3]; return v;
}

// ---------------- world-message kernel (fp32 VALU) ----------------
__global__ __launch_bounds__(256) void world_kernel(
    const float* __restrict__ z_h, const float* __restrict__ pos_world,
    const float* __restrict__ Ww1, const float* __restrict__ bw1,
    const float* __restrict__ Ww2, const float* __restrict__ bw2,
    float* __restrict__ m_agg_w)
{
    __shared__ float W1s[67 * 128];
    __shared__ float b1s[128];
    __shared__ float red[64];
    int t = threadIdx.x;
    for (int i = t; i < 67 * 128; i += 256) W1s[i] = Ww1[i];
    if (t < 128) b1s[t] = bw1[t];
    if (t < 64) red[t] = 0.f;
    __syncthreads();

    int node = blockIdx.x * 256 + t;
    float out[64];
#pragma unroll
    for (int o = 0; o < 64; o++) out[o] = 0.f;

    if (node < NN) {
        float x[67];
        const float4* zr = (const float4*)(z_h + (long)node * 64);
#pragma unroll
        for (int k = 0; k < 16; k++) {
            float4 v = zr[k];
            x[4 * k + 0] = v.x; x[4 * k + 1] = v.y; x[4 * k + 2] = v.z; x[4 * k + 3] = v.w;
        }
        x[64] = x[0] - pos_world[0];
        x[65] = x[1] - pos_world[1];
        x[66] = x[2] - pos_world[2];
#pragma unroll
        for (int o = 0; o < 64; o++) out[o] = bw2[o];

#pragma unroll 1
        for (int c = 0; c < 128; c += 4) {
            float h0 = b1s[c + 0], h1 = b1s[c + 1], h2 = b1s[c + 2], h3 = b1s[c + 3];
#pragma unroll
            for (int j = 0; j < 67; j++) {
                float xv = x[j];
                h0 += xv * W1s[j * 128 + c + 0];
                h1 += xv * W1s[j * 128 + c + 1];
                h2 += xv * W1s[j * 128 + c + 2];
                h3 += xv * W1s[j * 128 + c + 3];
            }
            h0 = fmaxf(h0, 0.f); h1 = fmaxf(h1, 0.f);
            h2 = fmaxf(h2, 0.f); h3 = fmaxf(h3, 0.f);
            const float* w2 = Ww2 + c * 64;
#pragma unroll
            for (int o = 0; o < 64; o++)
                out[o] += h0 * w2[o] + h1 * w2[64 + o] + h2 * w2[128 + o] + h3 * w2[192 + o];
        }
    }

#pragma unroll
    for (int mask = 1; mask < 64; mask <<= 1) {
#pragma unroll
        for (int o = 0; o < 64; o++) out[o] += __shfl_xor(out[o], mask, 64);
    }
    if ((t & 63) == 0) {
#pragma unroll
        for (int o = 0; o < 64; o++) atomicAdd(&red[o], out[o]);
    }
    __syncthreads();
    if (t < 64) atomicAdd(&m_agg_w[t], red[t]);
}

// ---------------- edge kernel: MFMA bf16, fragment-linear LDS ----------------
// All MFMA operands stored as 16B chunks at (chunk_index)*16B with
// chunk_index = (tile)*64 + lane  ->  every b128 access is base+lane*16B:
// balanced across all 32 banks (optimal 8-phase), zero excess conflicts.
//
// XF  chunk (kc*4+mt)*64+lane : X[mt*16+(lane&15)][kc*32+(lane>>4)*8+i], K pad 160
// WtF chunk (w*4+nt)*64+lane  : W1[kc*32+(lane>>4)*8+i][w*64+nt*16+(lane&15)]
// HF  chunk (kc*4+mt)*64+lane : H[mt*16+(lane&15)][kc*32+(lane>>4)*8+i]
// W2F chunk (kc*4+w)*64+lane  : We2[kc*32+(lane>>4)*8+i][w*16+(lane&15)]
union EdgeLds {
    struct { bf16x8 XF[1280]; bf16x8 WtF[1024]; } a;   // 20480 + 16384 B
    struct { bf16x8 HF[1024]; bf16x8 W2F[1024]; } b;   // 32768 B
};

__global__ __launch_bounds__(256) void edge_kernel(
    const float* __restrict__ z_h, const int* __restrict__ ei,
    const float* __restrict__ We1, const float* __restrict__ be1,
    const float* __restrict__ We2, const float* __restrict__ be2,
    const float* __restrict__ Wg1, const float* __restrict__ bg1,
    const float* __restrict__ Wg2, const float* __restrict__ bg2,
    float* __restrict__ m_agg_h)
{
    __shared__ EdgeLds L;
    __shared__ int   tgt_s[64];
    __shared__ float wgt[64];
    __shared__ float gred2[2][64];

    const int t = threadIdx.x;
    const int e0 = blockIdx.x * 64;          // NE % 64 == 0
    const int lane = t & 63, w = t >> 6;
    const int quad = lane >> 4, l16 = lane & 15;

    if (t < 64) tgt_s[t] = ei[NE + e0 + t];

    // ---- gather X tile into fragment-linear XF ----
    {
        const int ee = t >> 2, q = t & 3;
        const int mt = ee >> 4, l16e = ee & 15;
        const int s = ei[e0 + ee];
        const int d = ei[NE + e0 + ee];
        const float4* zs4 = (const float4*)(z_h + (long)s * 64) + q * 4;
        const float4* zt4 = (const float4*)(z_h + (long)d * 64) + q * 4;
        float4 s0 = zs4[0], s1 = zs4[1], s2 = zs4[2], s3 = zs4[3];
        float4 t0 = zt4[0], t1 = zt4[1], t2 = zt4[2], t3 = zt4[3];
        const int kcs = q >> 1, qa = (q & 1) * 2;
        L.a.XF[(kcs * 4 + mt) * 64 + qa * 16 + l16e]           = pack8(s0, s1);
        L.a.XF[(kcs * 4 + mt) * 64 + (qa + 1) * 16 + l16e]     = pack8(s2, s3);
        L.a.XF[((kcs + 2) * 4 + mt) * 64 + qa * 16 + l16e]     = pack8(t0, t1);
        L.a.XF[((kcs + 2) * 4 + mt) * 64 + (qa + 1) * 16 + l16e] = pack8(t2, t3);
        if (q == 0) {   // edge features -> cols 128..135 (kc=4, quad=0)
            float dx = s0.x - t0.x, dy = s0.y - t0.y, dz = s0.z - t0.z;
            float ax = s0.w, ay = s1.x, az = s1.y;
            float bx = t0.w, by = t1.x, bz = t1.y;
            float cx = ay * bz - az * by;
            float cy = az * bx - ax * bz;
            float cz = ax * by - ay * bx;
            bf16x8 f;
            f[0] = (__bf16)dx; f[1] = (__bf16)dy; f[2] = (__bf16)dz;
            f[3] = (__bf16)(dx * dx + dy * dy + dz * dz);
            f[4] = (__bf16)cx; f[5] = (__bf16)cy; f[6] = (__bf16)cz;
            f[7] = (__bf16)sqrtf(cx * cx + cy * cy + cz * cz);
            L.a.XF[(16 + mt) * 64 + l16e] = f;
        } else {        // zero pad cols 136..159 (kc=4, quad=q)
            bf16x8 z;
#pragma unroll
            for (int i = 0; i < 8; i++) z[i] = (__bf16)0.f;
            L.a.XF[(16 + mt) * 64 + q * 16 + l16e] = z;
        }
    }

    // ---- GEMM1: [64 x 160] @ [160 x 256] (We1 || Wg1), wave owns 64 cols ----
    const int colb = w * 64;
    f32x4 acc1[4][4];
#pragma unroll
    for (int nt = 0; nt < 4; nt++) {
        int col = colb + nt * 16 + l16;
        float b = (col < 128) ? be1[col] : bg1[col - 128];
#pragma unroll
        for (int mt = 0; mt < 4; mt++) { f32x4 v = {b, b, b, b}; acc1[mt][nt] = v; }
    }

#pragma unroll 1
    for (int kc = 0; kc < 5; kc++) {
        __syncthreads();
        {   // stage WtF (4 chunks/thread, chunk c = t + 256*j -> wave j's cols)
            const int nt_s = (t >> 6) & 3, lc = t & 63;
            const int colr = nt_s * 16 + (t & 15);
            const int row0 = kc * 32 + ((t >> 4) & 3) * 8;
#pragma unroll
            for (int j = 0; j < 4; j++) {
                int col = j * 64 + colr;
                const float* src = (col < 128) ? (We1 + col) : (Wg1 + (col - 128));
                bf16x8 p;
#pragma unroll
                for (int i = 0; i < 8; i++) {
                    int r = row0 + i;
                    p[i] = (__bf16)((r < 136) ? src[(size_t)r * 128] : 0.f);
                }
                L.a.WtF[(j * 4 + nt_s) * 64 + lc] = p;
            }
        }
        __syncthreads();
        bf16x8 af[4], bfr[4];
#pragma unroll
        for (int mt = 0; mt < 4; mt++) af[mt] = L.a.XF[(kc * 4 + mt) * 64 + lane];
#pragma unroll
        for (int nt = 0; nt < 4; nt++) bfr[nt] = L.a.WtF[(w * 4 + nt) * 64 + lane];
#pragma unroll
        for (int mt = 0; mt < 4; mt++)
#pragma unroll
            for (int nt = 0; nt < 4; nt++)
                acc1[mt][nt] = __builtin_amdgcn_mfma_f32_16x16x32_bf16(
                    af[mt], bfr[nt], acc1[mt][nt], 0, 0, 0);
    }

    __syncthreads();   // phase-A LDS reads complete; union repurposed below

    // ---- waves 0,1: write H (relu) in GEMM2-A fragment order ----
    if (w < 2) {
        __bf16* HFp = (__bf16*)L.b.HF;
#pragma unroll
        for (int nt = 0; nt < 4; nt++) {
            int col = w * 64 + nt * 16 + l16;
            int kc2 = col >> 5, quad2 = (col >> 3) & 3, ii = col & 7;
#pragma unroll
            for (int mt = 0; mt < 4; mt++)
#pragma unroll
                for (int r = 0; r < 4; r++)
                    HFp[(((kc2 * 4 + mt) * 64) + quad2 * 16 + quad * 4 + r) * 8 + ii] =
                        (__bf16)fmaxf(acc1[mt][nt][r], 0.f);
        }
    } else {
        // ---- waves 2,3: gate partials in-register from acc1 (gate cols) ----
        float gp[4][4];
#pragma unroll
        for (int mt = 0; mt < 4; mt++)
#pragma unroll
            for (int r = 0; r < 4; r++) gp[mt][r] = 0.f;
#pragma unroll
        for (int nt = 0; nt < 4; nt++) {
            float wg = Wg2[(w - 2) * 64 + nt * 16 + l16];
#pragma unroll
            for (int mt = 0; mt < 4; mt++)
#pragma unroll
                for (int r = 0; r < 4; r++)
                    gp[mt][r] += fmaxf(acc1[mt][nt][r], 0.f) * wg;
        }
#pragma unroll
        for (int mask = 1; mask < 16; mask <<= 1)
#pragma unroll
            for (int mt = 0; mt < 4; mt++)
#pragma unroll
                for (int r = 0; r < 4; r++)
                    gp[mt][r] += __shfl_xor(gp[mt][r], mask, 64);
        if (l16 == 0) {
#pragma unroll
            for (int mt = 0; mt < 4; mt++)
#pragma unroll
                for (int r = 0; r < 4; r++)
                    gred2[w - 2][mt * 16 + quad * 4 + r] = gp[mt][r];
        }
    }
    {   // ---- stage We2 fragments (all threads, 4 chunks) ----
        const int wv = (t >> 6) & 3, lc = t & 63;
        const int col = wv * 16 + (t & 15);
        const int row0b = ((t >> 4) & 3) * 8;
#pragma unroll
        for (int j = 0; j < 4; j++) {          // j = kc2
            bf16x8 p;
#pragma unroll
            for (int i = 0; i < 8; i++)
                p[i] = (__bf16)We2[(size_t)(j * 32 + row0b + i) * 64 + col];
            L.b.W2F[(j * 4 + wv) * 64 + lc] = p;
        }
    }
    __syncthreads();
    if (t < 64) {
        float g = bg2[0] + gred2[0][t] + gred2[1][t];
        wgt[t] = 1.f / (1.f + expf(-g));
    }
    __syncthreads();

    // ---- GEMM2: message = H[:,0:128] @ We2 + be2 ----
    f32x4 acc2[4];
    {
        float b2 = be2[w * 16 + l16];
#pragma unroll
        for (int mt = 0; mt < 4; mt++) { f32x4 v = {b2, b2, b2, b2}; acc2[mt] = v; }
    }
#pragma unroll
    for (int kc = 0; kc < 4; kc++) {
        bf16x8 b2f = L.b.W2F[(kc * 4 + w) * 64 + lane];
#pragma unroll
        for (int mt = 0; mt < 4; mt++)
            acc2[mt] = __builtin_amdgcn_mfma_f32_16x16x32_bf16(
                L.b.HF[(kc * 4 + mt) * 64 + lane], b2f, acc2[mt], 0, 0, 0);
    }

    // ---- scatter: atomicAdd(w * m) into target rows ----
#pragma unroll
    for (int mt = 0; mt < 4; mt++)
#pragma unroll
        for (int r = 0; r < 4; r++) {
            int edge = mt * 16 + quad * 4 + r;
            float val = acc2[mt][r] * wgt[edge];
            atomicAdd(m_agg_h + (long)tgt_s[edge] * 64 + w * 16 + l16, val);
        }
}

// ---------------- node kernel: MFMA bf16, fragment-linear LDS ----------------
union NodeLds {
    struct { bf16x8 XF[1024]; bf16x8 WtF[512]; } a;    // 16384 + 8192 B
    struct { bf16x8 HF[1024]; bf16x8 W2F[1024]; } b;   // 32768 B
};

__global__ __launch_bounds__(256) void node_kernel(
    const float* __restrict__ z_h,
    const float* __restrict__ m_agg_h, const float* __restrict__ m_agg_w,
    const float* __restrict__ Wn1, const float* __restrict__ bn1,
    const float* __restrict__ Wn2, const float* __restrict__ bn2,
    float* __restrict__ outp)
{
    __shared__ NodeLds L;
    __shared__ float mw[64];
    const int t = threadIdx.x;
    const int n0 = blockIdx.x * 64;
    const int lane = t & 63, w = t >> 6;
    const int quad = lane >> 4, l16 = lane & 15;

    if (t < 64) mw[t] = m_agg_w[t];
    __syncthreads();

    {   // gather [z | m_agg_h + mw] -> fragment-linear XF
        const int nn = t >> 2, q = t & 3;
        const int mt = nn >> 4, l16e = nn & 15;
        int node = n0 + nn; if (node >= NN) node = NN - 1;   // clamp stays in-block
        const float4* zr = (const float4*)(z_h + (long)node * 64) + q * 4;
        const float4* mr = (const float4*)(m_agg_h + (long)node * 64) + q * 4;
        float4 z0 = zr[0], z1 = zr[1], z2 = zr[2], z3 = zr[3];
        float4 m0 = mr[0], m1 = mr[1], m2 = mr[2], m3 = mr[3];
        const float* mwp = &mw[q * 16];
        m0 = addw(m0, mwp); m1 = addw(m1, mwp + 4);
        m2 = addw(m2, mwp + 8); m3 = addw(m3, mwp + 12);
        const int kcs = q >> 1, qa = (q & 1) * 2;
        L.a.XF[(kcs * 4 + mt) * 64 + qa * 16 + l16e]             = pack8(z0, z1);
        L.a.XF[(kcs * 4 + mt) * 64 + (qa + 1) * 16 + l16e]       = pack8(z2, z3);
        L.a.XF[((kcs + 2) * 4 + mt) * 64 + qa * 16 + l16e]       = pack8(m0, m1);
        L.a.XF[((kcs + 2) * 4 + mt) * 64 + (qa + 1) * 16 + l16e] = pack8(m2, m3);
    }

    // ---- GEMM1: [64 x 128] @ [128 x 128], wave owns 32 cols ----
    f32x4 acc1[4][2];
#pragma unroll
    for (int nt = 0; nt < 2; nt++) {
        float b = bn1[w * 32 + nt * 16 + l16];
#pragma unroll
        for (int mt = 0; mt < 4; mt++) { f32x4 v = {b, b, b, b}; acc1[mt][nt] = v; }
    }

#pragma unroll 1
    for (int kc = 0; kc < 4; kc++) {
        __syncthreads();
        {   // stage WtF (2 chunks/thread)
            const int lc = t & 63;
            const int row0 = kc * 32 + ((t >> 4) & 3) * 8;
#pragma unroll
            for (int j = 0; j < 2; j++) {
                int idx8 = (t >> 6) + 4 * j;          // (w*2+nt) of the chunk
                int col = (idx8 >> 1) * 32 + (idx8 & 1) * 16 + (t & 15);
                bf16x8 p;
#pragma unroll
                for (int i = 0; i < 8; i++)
                    p[i] = (__bf16)Wn1[(size_t)(row0 + i) * 128 + col];
                L.a.WtF[idx8 * 64 + lc] = p;
            }
        }
        __syncthreads();
        bf16x8 af[4], bfr[2];
#pragma unroll
        for (int mt = 0; mt < 4; mt++) af[mt] = L.a.XF[(kc * 4 + mt) * 64 + lane];
#pragma unroll
        for (int nt = 0; nt < 2; nt++) bfr[nt] = L.a.WtF[(w * 2 + nt) * 64 + lane];
#pragma unroll
        for (int mt = 0; mt < 4; mt++)
#pragma unroll
            for (int nt = 0; nt < 2; nt++)
                acc1[mt][nt] = __builtin_amdgcn_mfma_f32_16x16x32_bf16(
                    af[mt], bfr[nt], acc1[mt][nt], 0, 0, 0);
    }

    __syncthreads();

    {   // H (relu) -> fragment-linear HF; all waves write their 32 cols
        __bf16* HFp = (__bf16*)L.b.HF;
#pragma unroll
        for (int nt = 0; nt < 2; nt++) {
            int col = w * 32 + nt * 16 + l16;
            int kc2 = w, quad2 = nt * 2 + (l16 >> 3), ii = l16 & 7;
#pragma unroll
            for (int mt = 0; mt < 4; mt++)
#pragma unroll
                for (int r = 0; r < 4; r++)
                    HFp[(((kc2 * 4 + mt) * 64) + quad2 * 16 + quad * 4 + r) * 8 + ii] =
                        (__bf16)fmaxf(acc1[mt][nt][r], 0.f);
        }
    }
    {   // stage Wn2 fragments
        const int wv = (t >> 6) & 3, lc = t & 63;
        const int col = wv * 16 + (t & 15);
        const int row0b = ((t >> 4) & 3) * 8;
#pragma unroll
        for (int j = 0; j < 4; j++) {
            bf16x8 p;
#pragma unroll
            for (int i = 0; i < 8; i++)
                p[i] = (__bf16)Wn2[(size_t)(j * 32 + row0b + i) * 64 + col];
            L.b.W2F[(j * 4 + wv) * 64 + lc] = p;
        }
    }
    __syncthreads();

    f32x4 acc2[4];
    {
        float b2 = bn2[w * 16 + l16];
#pragma unroll
        for (int mt = 0; mt < 4; mt++) { f32x4 v = {b2, b2, b2, b2}; acc2[mt] = v; }
    }
#pragma unroll
    for (int kc = 0; kc < 4; kc++) {
        bf16x8 b2f = L.b.W2F[(kc * 4 + w) * 64 + lane];
#pragma unroll
        for (int mt = 0; mt < 4; mt++)
            acc2[mt] = __builtin_amdgcn_mfma_f32_16x16x32_bf16(
                L.b.HF[(kc * 4 + mt) * 64 + lane], b2f, acc2[mt], 0, 0, 0);
    }

#pragma unroll
    for (int mt = 0; mt < 4; mt++)
#pragma unroll
        for (int r = 0; r < 4; r++) {
            int node = n0 + mt * 16 + quad * 4 + r;
            if (node < NN)
                outp[(long)node * 64 + w * 16 + l16] = acc2[mt][r];
        }
}

extern "C" void kernel_launch(void* const* d_in, const int* in_sizes, int n_in,
                              void* d_out, int out_size, void* d_ws, size_t ws_size,
                              hipStream_t stream)
{
    const float* z_h       = (const float*)d_in[0];
    const float* pos_world = (const float*)d_in[1];
    const int*   ei        = (const int*)d_in[2];
    const float* We1 = (const float*)d_in[3];  const float* be1 = (const float*)d_in[4];
    const float* We2 = (const float*)d_in[5];  const float* be2 = (const float*)d_in[6];
    const float* Wg1 = (const float*)d_in[7];  const float* bg1 = (const float*)d_in[8];
    const float* Wg2 = (const float*)d_in[9];  const float* bg2 = (const float*)d_in[10];
    const float* Wn1 = (const float*)d_in[11]; const float* bn1 = (const float*)d_in[12];
    const float* Wn2 = (const float*)d_in[13]; const float* bn2 = (const float*)d_in[14];
    const float* Ww1 = (const float*)d_in[15]; const float* bw1 = (const float*)d_in[16];
    const float* Ww2 = (const float*)d_in[17]; const float* bw2 = (const float*)d_in[18];

    float* outp    = (float*)d_out;
    float* m_agg_h = outp;             // d_out doubles as the scatter accumulator
    float* m_agg_w = (float*)d_ws;     // 64 floats of ws

    hipMemsetAsync(d_out, 0, (size_t)NN * 64 * sizeof(float), stream);
    hipMemsetAsync(d_ws, 0, 64 * sizeof(float), stream);

    world_kernel<<<(NN + 255) / 256, 256, 0, stream>>>(z_h, pos_world, Ww1, bw1, Ww2, bw2, m_agg_w);
    edge_kernel<<<NE / 64, 256, 0, stream>>>(z_h, ei, We1, be1, We2, be2,
                                             Wg1, bg1, Wg2, bg2, m_agg_h);
    node_kernel<<<(NN + 63) / 64, 256, 0, stream>>>(z_h, m_agg_h, m_agg_w,
                                                    Wn1, bn1, Wn2, bn2, outp);
}

// Round 4
// 482.605 us; speedup vs baseline: 11.0738x; 1.7961x over previous
//
#include <hip/hip_runtime.h>
#include <math.h>

#define NN 50000
#define NE 800000

typedef float  f32x4  __attribute__((ext_vector_type(4)));
typedef __bf16 bf16x8 __attribute__((ext_vector_type(8)));

// ws layout (bytes):
//   [0,256)        m_agg_w (64 f32, zeroed each call)
//   [256, ...)     bf16 weight fragments, 16B chunks, fragment-linear:
//     We1F: 5120 chunks  (kc<5, ct<16, lane<64)   [We1 || Wg1, K padded to 160]
//     We2F: 1024 chunks  (kc<4, wv<4,  lane<64)
//     Wn1F: 2048 chunks  (kc<4, ct<8,  lane<64)
//     Wn2F: 1024 chunks  (kc<4, wv<4,  lane<64)
#define WE1F_OFF 0
#define WE2F_OFF 5120
#define WN1F_OFF 6144
#define WN2F_OFF 8192
#define NCHUNKS  9216

__device__ inline bf16x8 pack8(float4 a, float4 b) {
    bf16x8 r;
    r[0] = (__bf16)a.x; r[1] = (__bf16)a.y; r[2] = (__bf16)a.z; r[3] = (__bf16)a.w;
    r[4] = (__bf16)b.x; r[5] = (__bf16)b.y; r[6] = (__bf16)b.z; r[7] = (__bf16)b.w;
    return r;
}

// ---------------- weight fragment pre-pack (runs once per call) ----------------
__global__ __launch_bounds__(256) void pack_weights(
    const float* __restrict__ We1, const float* __restrict__ Wg1,
    const float* __restrict__ We2, const float* __restrict__ Wn1,
    const float* __restrict__ Wn2, bf16x8* __restrict__ wsF)
{
    int c = blockIdx.x * 256 + threadIdx.x;
    if (c >= NCHUNKS) return;
    const int lane = c & 63, l16 = lane & 15, row8 = ((lane >> 4) & 3) * 8;
    bf16x8 p;
    if (c < WE2F_OFF) {                       // We1 || Wg1, zero-pad K 136->160
        int ct = (c >> 6) & 15, kc = c >> 10;
        int col = ct * 16 + l16;
        const float* src = (col < 128) ? (We1 + col) : (Wg1 + (col - 128));
#pragma unroll
        for (int i = 0; i < 8; i++) {
            int r = kc * 32 + row8 + i;
            p[i] = (__bf16)((r < 136) ? src[(size_t)r * 128] : 0.f);
        }
    } else if (c < WN1F_OFF) {
        int cc = c - WE2F_OFF; int wv = (cc >> 6) & 3, kc = cc >> 8;
        int col = wv * 16 + l16;
#pragma unroll
        for (int i = 0; i < 8; i++)
            p[i] = (__bf16)We2[(size_t)(kc * 32 + row8 + i) * 64 + col];
    } else if (c < WN2F_OFF) {
        int cc = c - WN1F_OFF; int ct = (cc >> 6) & 7, kc = cc >> 9;
        int col = ct * 16 + l16;
#pragma unroll
        for (int i = 0; i < 8; i++)
            p[i] = (__bf16)Wn1[(size_t)(kc * 32 + row8 + i) * 128 + col];
    } else {
        int cc = c - WN2F_OFF; int wv = (cc >> 6) & 3, kc = cc >> 8;
        int col = wv * 16 + l16;
#pragma unroll
        for (int i = 0; i < 8; i++)
            p[i] = (__bf16)Wn2[(size_t)(kc * 32 + row8 + i) * 64 + col];
    }
    wsF[c] = p;
}

// ---------------- world-message kernel (fp32 VALU) ----------------
__global__ __launch_bounds__(256) void world_kernel(
    const float* __restrict__ z_h, const float* __restrict__ pos_world,
    const float* __restrict__ Ww1, const float* __restrict__ bw1,
    const float* __restrict__ Ww2, const float* __restrict__ bw2,
    float* __restrict__ m_agg_w)
{
    __shared__ float W1s[67 * 128];
    __shared__ float b1s[128];
    __shared__ float red[64];
    int t = threadIdx.x;
    for (int i = t; i < 67 * 128; i += 256) W1s[i] = Ww1[i];
    if (t < 128) b1s[t] = bw1[t];
    if (t < 64) red[t] = 0.f;
    __syncthreads();

    int node = blockIdx.x * 256 + t;
    float out[64];
#pragma unroll
    for (int o = 0; o < 64; o++) out[o] = 0.f;

    if (node < NN) {
        float x[67];
        const float4* zr = (const float4*)(z_h + (long)node * 64);
#pragma unroll
        for (int k = 0; k < 16; k++) {
            float4 v = zr[k];
            x[4 * k + 0] = v.x; x[4 * k + 1] = v.y; x[4 * k + 2] = v.z; x[4 * k + 3] = v.w;
        }
        x[64] = x[0] - pos_world[0];
        x[65] = x[1] - pos_world[1];
        x[66] = x[2] - pos_world[2];
#pragma unroll
        for (int o = 0; o < 64; o++) out[o] = bw2[o];

#pragma unroll 1
        for (int c = 0; c < 128; c += 4) {
            float h0 = b1s[c + 0], h1 = b1s[c + 1], h2 = b1s[c + 2], h3 = b1s[c + 3];
#pragma unroll
            for (int j = 0; j < 67; j++) {
                float xv = x[j];
                h0 += xv * W1s[j * 128 + c + 0];
                h1 += xv * W1s[j * 128 + c + 1];
                h2 += xv * W1s[j * 128 + c + 2];
                h3 += xv * W1s[j * 128 + c + 3];
            }
            h0 = fmaxf(h0, 0.f); h1 = fmaxf(h1, 0.f);
            h2 = fmaxf(h2, 0.f); h3 = fmaxf(h3, 0.f);
            const float* w2 = Ww2 + c * 64;
#pragma unroll
            for (int o = 0; o < 64; o++)
                out[o] += h0 * w2[o] + h1 * w2[64 + o] + h2 * w2[128 + o] + h3 * w2[192 + o];
        }
    }

#pragma unroll
    for (int mask = 1; mask < 64; mask <<= 1) {
#pragma unroll
        for (int o = 0; o < 64; o++) out[o] += __shfl_xor(out[o], mask, 64);
    }
    if ((t & 63) == 0) {
#pragma unroll
        for (int o = 0; o < 64; o++) atomicAdd(&red[o], out[o]);
    }
    __syncthreads();
    if (t < 64) atomicAdd(&m_agg_w[t], red[t]);
}

// ---------------- edge kernel: MFMA bf16, weights direct from L2 ----------------
// 64 edges/block, 4 waves. B-fragments come straight from pre-packed ws
// (coalesced dwordx4, no LDS, no staging barriers). Only X and H live in LDS,
// in fragment-linear order (every access = base + lane*16B). 2 barriers total.
__global__ __launch_bounds__(256, 4) void edge_kernel(
    const float* __restrict__ z_h, const int* __restrict__ ei,
    const bf16x8* __restrict__ We1F, const bf16x8* __restrict__ We2F,
    const float* __restrict__ be1, const float* __restrict__ be2,
    const float* __restrict__ bg1, const float* __restrict__ Wg2,
    const float* __restrict__ bg2,
    float* __restrict__ m_agg_h)
{
    __shared__ bf16x8 XF[1280];     // 20 KB: X [64 x 160]
    __shared__ bf16x8 HF[1024];     // 16 KB: H [64 x 128] in GEMM2-A order
    __shared__ int   tgt_s[64];
    __shared__ float gred2[2][64];

    const int t = threadIdx.x;
    const int e0 = blockIdx.x * 64;          // NE % 64 == 0
    const int lane = t & 63, w = t >> 6;
    const int quad = lane >> 4, l16 = lane & 15;

    if (t < 64) tgt_s[t] = ei[NE + e0 + t];

    // ---- gather: wave w owns edges w*16..w*16+15; lane = q*16 + l16e ----
    {
        const int ee = w * 16 + l16;         // mt == w
        const int q = quad;
        const int s = ei[e0 + ee];
        const int d = ei[NE + e0 + ee];
        const float4* zs4 = (const float4*)(z_h + (long)s * 64) + q * 4;
        const float4* zt4 = (const float4*)(z_h + (long)d * 64) + q * 4;
        float4 s0 = zs4[0], s1 = zs4[1], s2 = zs4[2], s3 = zs4[3];
        float4 t0 = zt4[0], t1 = zt4[1], t2 = zt4[2], t3 = zt4[3];
        const int kcs = q >> 1, qa = (q & 1) * 2;
        XF[(kcs * 4 + w) * 64 + qa * 16 + l16]             = pack8(s0, s1);
        XF[(kcs * 4 + w) * 64 + (qa + 1) * 16 + l16]       = pack8(s2, s3);
        XF[((kcs + 2) * 4 + w) * 64 + qa * 16 + l16]       = pack8(t0, t1);
        XF[((kcs + 2) * 4 + w) * 64 + (qa + 1) * 16 + l16] = pack8(t2, t3);
        if (q == 0) {   // edge features -> cols 128..135
            float dx = s0.x - t0.x, dy = s0.y - t0.y, dz = s0.z - t0.z;
            float ax = s0.w, ay = s1.x, az = s1.y;
            float bx = t0.w, by = t1.x, bz = t1.y;
            float cx = ay * bz - az * by;
            float cy = az * bx - ax * bz;
            float cz = ax * by - ay * bx;
            bf16x8 f;
            f[0] = (__bf16)dx; f[1] = (__bf16)dy; f[2] = (__bf16)dz;
            f[3] = (__bf16)(dx * dx + dy * dy + dz * dz);
            f[4] = (__bf16)cx; f[5] = (__bf16)cy; f[6] = (__bf16)cz;
            f[7] = (__bf16)sqrtf(cx * cx + cy * cy + cz * cz);
            XF[(16 + w) * 64 + l16] = f;
        } else {        // zero pad cols 136..159
            bf16x8 z;
#pragma unroll
            for (int i = 0; i < 8; i++) z[i] = (__bf16)0.f;
            XF[(16 + w) * 64 + q * 16 + l16] = z;
        }
    }

    // ---- acc init: wave owns 64 cols of [We1 || Wg1] ----
    f32x4 acc1[4][4];
#pragma unroll
    for (int nt = 0; nt < 4; nt++) {
        int col = w * 64 + nt * 16 + l16;
        float b = (col < 128) ? be1[col] : bg1[col - 128];
#pragma unroll
        for (int mt = 0; mt < 4; mt++) { f32x4 v = {b, b, b, b}; acc1[mt][nt] = v; }
    }
    __syncthreads();                         // barrier 1: XF ready

    // ---- GEMM1: straight-line, no barriers, B-frags from L2 ----
#pragma unroll
    for (int kc = 0; kc < 5; kc++) {
        bf16x8 af[4], bfr[4];
#pragma unroll
        for (int mt = 0; mt < 4; mt++) af[mt] = XF[(kc * 4 + mt) * 64 + lane];
#pragma unroll
        for (int nt = 0; nt < 4; nt++)
            bfr[nt] = We1F[(kc * 16 + w * 4 + nt) * 64 + lane];
#pragma unroll
        for (int mt = 0; mt < 4; mt++)
#pragma unroll
            for (int nt = 0; nt < 4; nt++)
                acc1[mt][nt] = __builtin_amdgcn_mfma_f32_16x16x32_bf16(
                    af[mt], bfr[nt], acc1[mt][nt], 0, 0, 0);
    }

    if (w < 2) {
        // ---- waves 0,1: write H (relu) in GEMM2-A fragment order ----
        __bf16* HFp = (__bf16*)HF;
#pragma unroll
        for (int nt = 0; nt < 4; nt++) {
            int col = w * 64 + nt * 16 + l16;
            int kc2 = col >> 5, quad2 = (col >> 3) & 3, ii = col & 7;
#pragma unroll
            for (int mt = 0; mt < 4; mt++)
#pragma unroll
                for (int r = 0; r < 4; r++)
                    HFp[(((kc2 * 4 + mt) * 64) + quad2 * 16 + quad * 4 + r) * 8 + ii] =
                        (__bf16)fmaxf(acc1[mt][nt][r], 0.f);
        }
    } else {
        // ---- waves 2,3: gate partials in-register ----
        float gp[4][4];
#pragma unroll
        for (int mt = 0; mt < 4; mt++)
#pragma unroll
            for (int r = 0; r < 4; r++) gp[mt][r] = 0.f;
#pragma unroll
        for (int nt = 0; nt < 4; nt++) {
            float wg = Wg2[(w - 2) * 64 + nt * 16 + l16];
#pragma unroll
            for (int mt = 0; mt < 4; mt++)
#pragma unroll
                for (int r = 0; r < 4; r++)
                    gp[mt][r] += fmaxf(acc1[mt][nt][r], 0.f) * wg;
        }
#pragma unroll
        for (int mask = 1; mask < 16; mask <<= 1)
#pragma unroll
            for (int mt = 0; mt < 4; mt++)
#pragma unroll
                for (int r = 0; r < 4; r++)
                    gp[mt][r] += __shfl_xor(gp[mt][r], mask, 64);
        if (l16 == 0) {
#pragma unroll
            for (int mt = 0; mt < 4; mt++)
#pragma unroll
                for (int r = 0; r < 4; r++)
                    gred2[w - 2][mt * 16 + quad * 4 + r] = gp[mt][r];
        }
    }
    __syncthreads();                         // barrier 2: HF + gred2 ready

    // ---- GEMM2: message = H[:,0:128] @ We2 + be2 ----
    f32x4 acc2[4];
    {
        float b2 = be2[w * 16 + l16];
#pragma unroll
        for (int mt = 0; mt < 4; mt++) { f32x4 v = {b2, b2, b2, b2}; acc2[mt] = v; }
    }
#pragma unroll
    for (int kc = 0; kc < 4; kc++) {
        bf16x8 b2f = We2F[(kc * 4 + w) * 64 + lane];
#pragma unroll
        for (int mt = 0; mt < 4; mt++)
            acc2[mt] = __builtin_amdgcn_mfma_f32_16x16x32_bf16(
                HF[(kc * 4 + mt) * 64 + lane], b2f, acc2[mt], 0, 0, 0);
    }

    // ---- sigmoid (broadcast LDS reads) + scatter ----
    const float bg2v = bg2[0];
#pragma unroll
    for (int mt = 0; mt < 4; mt++)
#pragma unroll
        for (int r = 0; r < 4; r++) {
            int edge = mt * 16 + quad * 4 + r;
            float g = bg2v + gred2[0][edge] + gred2[1][edge];
            float wgt = 1.f / (1.f + expf(-g));
            atomicAdd(m_agg_h + (long)tgt_s[edge] * 64 + w * 16 + l16,
                      acc2[mt][r] * wgt);
        }
}

// ---------------- node kernel: MFMA bf16, weights direct from L2 ----------------
__global__ __launch_bounds__(256, 4) void node_kernel(
    const float* __restrict__ z_h,
    const float* __restrict__ m_agg_h, const float* __restrict__ m_agg_w,
    const bf16x8* __restrict__ Wn1F, const bf16x8* __restrict__ Wn2F,
    const float* __restrict__ bn1, const float* __restrict__ bn2,
    float* __restrict__ outp)
{
    __shared__ bf16x8 XF[1024];     // 16 KB
    __shared__ bf16x8 HF[1024];     // 16 KB
    const int t = threadIdx.x;
    const int n0 = blockIdx.x * 64;
    const int lane = t & 63, w = t >> 6;
    const int quad = lane >> 4, l16 = lane & 15;

    {   // gather [z | m_agg_h + m_agg_w] -> fragment-linear XF
        const int nn = w * 16 + l16;         // mt == w
        const int q = quad;
        int node = n0 + nn; if (node >= NN) node = NN - 1;   // clamp in-block
        const float4* zr = (const float4*)(z_h + (long)node * 64) + q * 4;
        const float4* mr = (const float4*)(m_agg_h + (long)node * 64) + q * 4;
        const float4* mwg = (const float4*)m_agg_w + q * 4;
        float4 z0 = zr[0], z1 = zr[1], z2 = zr[2], z3 = zr[3];
        float4 m0 = mr[0], m1 = mr[1], m2 = mr[2], m3 = mr[3];
        float4 w0 = mwg[0], w1 = mwg[1], w2 = mwg[2], w3 = mwg[3];
        m0.x += w0.x; m0.y += w0.y; m0.z += w0.z; m0.w += w0.w;
        m1.x += w1.x; m1.y += w1.y; m1.z += w1.z; m1.w += w1.w;
        m2.x += w2.x; m2.y += w2.y; m2.z += w2.z; m2.w += w2.w;
        m3.x += w3.x; m3.y += w3.y; m3.z += w3.z; m3.w += w3.w;
        const int kcs = q >> 1, qa = (q & 1) * 2;
        XF[(kcs * 4 + w) * 64 + qa * 16 + l16]             = pack8(z0, z1);
        XF[(kcs * 4 + w) * 64 + (qa + 1) * 16 + l16]       = pack8(z2, z3);
        XF[((kcs + 2) * 4 + w) * 64 + qa * 16 + l16]       = pack8(m0, m1);
        XF[((kcs + 2) * 4 + w) * 64 + (qa + 1) * 16 + l16] = pack8(m2, m3);
    }

    f32x4 acc1[4][2];
#pragma unroll
    for (int nt = 0; nt < 2; nt++) {
        float b = bn1[w * 32 + nt * 16 + l16];
#pragma unroll
        for (int mt = 0; mt < 4; mt++) { f32x4 v = {b, b, b, b}; acc1[mt][nt] = v; }
    }
    __syncthreads();                         // barrier 1

#pragma unroll
    for (int kc = 0; kc < 4; kc++) {
        bf16x8 af[4], bfr[2];
#pragma unroll
        for (int mt = 0; mt < 4; mt++) af[mt] = XF[(kc * 4 + mt) * 64 + lane];
#pragma unroll
        for (int nt = 0; nt < 2; nt++)
            bfr[nt] = Wn1F[(kc * 8 + w * 2 + nt) * 64 + lane];
#pragma unroll
        for (int mt = 0; mt < 4; mt++)
#pragma unroll
            for (int nt = 0; nt < 2; nt++)
                acc1[mt][nt] = __builtin_amdgcn_mfma_f32_16x16x32_bf16(
                    af[mt], bfr[nt], acc1[mt][nt], 0, 0, 0);
    }

    {   // H (relu) -> fragment-linear HF
        __bf16* HFp = (__bf16*)HF;
#pragma unroll
        for (int nt = 0; nt < 2; nt++) {
            int col = w * 32 + nt * 16 + l16;
            int kc2 = w, quad2 = nt * 2 + (l16 >> 3), ii = l16 & 7;
#pragma unroll
            for (int mt = 0; mt < 4; mt++)
#pragma unroll
                for (int r = 0; r < 4; r++)
                    HFp[(((kc2 * 4 + mt) * 64) + quad2 * 16 + quad * 4 + r) * 8 + ii] =
                        (__bf16)fmaxf(acc1[mt][nt][r], 0.f);
        }
    }
    __syncthreads();                         // barrier 2

    f32x4 acc2[4];
    {
        float b2 = bn2[w * 16 + l16];
#pragma unroll
        for (int mt = 0; mt < 4; mt++) { f32x4 v = {b2, b2, b2, b2}; acc2[mt] = v; }
    }
#pragma unroll
    for (int kc = 0; kc < 4; kc++) {
        bf16x8 b2f = Wn2F[(kc * 4 + w) * 64 + lane];
#pragma unroll
        for (int mt = 0; mt < 4; mt++)
            acc2[mt] = __builtin_amdgcn_mfma_f32_16x16x32_bf16(
                HF[(kc * 4 + mt) * 64 + lane], b2f, acc2[mt], 0, 0, 0);
    }

#pragma unroll
    for (int mt = 0; mt < 4; mt++)
#pragma unroll
        for (int r = 0; r < 4; r++) {
            int node = n0 + mt * 16 + quad * 4 + r;
            if (node < NN)
                outp[(long)node * 64 + w * 16 + l16] = acc2[mt][r];
        }
}

extern "C" void kernel_launch(void* const* d_in, const int* in_sizes, int n_in,
                              void* d_out, int out_size, void* d_ws, size_t ws_size,
                              hipStream_t stream)
{
    const float* z_h       = (const float*)d_in[0];
    const float* pos_world = (const float*)d_in[1];
    const int*   ei        = (const int*)d_in[2];
    const float* We1 = (const float*)d_in[3];  const float* be1 = (const float*)d_in[4];
    const float* We2 = (const float*)d_in[5];  const float* be2 = (const float*)d_in[6];
    const float* Wg1 = (const float*)d_in[7];  const float* bg1 = (const float*)d_in[8];
    const float* Wg2 = (const float*)d_in[9];  const float* bg2 = (const float*)d_in[10];
    const float* Wn1 = (const float*)d_in[11]; const float* bn1 = (const float*)d_in[12];
    const float* Wn2 = (const float*)d_in[13]; const float* bn2 = (const float*)d_in[14];
    const float* Ww1 = (const float*)d_in[15]; const float* bw1 = (const float*)d_in[16];
    const float* Ww2 = (const float*)d_in[17]; const float* bw2 = (const float*)d_in[18];

    float*  outp    = (float*)d_out;
    float*  m_agg_h = outp;                 // d_out doubles as scatter accumulator
    float*  m_agg_w = (float*)d_ws;         // 64 floats
    bf16x8* wsF     = (bf16x8*)((char*)d_ws + 256);

    hipMemsetAsync(d_out, 0, (size_t)NN * 64 * sizeof(float), stream);
    hipMemsetAsync(d_ws, 0, 256, stream);

    pack_weights<<<(NCHUNKS + 255) / 256, 256, 0, stream>>>(We1, Wg1, We2, Wn1, Wn2, wsF);
    world_kernel<<<(NN + 255) / 256, 256, 0, stream>>>(z_h, pos_world, Ww1, bw1, Ww2, bw2, m_agg_w);
    edge_kernel<<<NE / 64, 256, 0, stream>>>(z_h, ei,
                                             wsF + WE1F_OFF, wsF + WE2F_OFF,
                                             be1, be2, bg1, Wg2, bg2, m_agg_h);
    node_kernel<<<(NN + 63) / 64, 256, 0, stream>>>(z_h, m_agg_h, m_agg_w,
                                                    wsF + WN1F_OFF, wsF + WN2F_OFF,
                                                    bn1, bn2, outp);
}